// Round 1
// baseline (1264.915 us; speedup 1.0000x reference)
//
#include <hip/hip_runtime.h>

#define B_SZ 64
#define N_SZ 1024
#define C1   64
#define C2   128
#define C3   256
#define H_SZ 256

// ------------------------------------------------------------------
// Spectral norm of A (256x256) via repeated squaring of B = A^T A,
// then Rayleigh quotient against original B0.
// ------------------------------------------------------------------
__global__ void k_btb(const float* __restrict__ A, float* __restrict__ B0) {
  int i = blockIdx.x;    // 0..255
  int j = threadIdx.x;   // 0..255
  float acc = 0.f;
  for (int k = 0; k < 256; ++k)
    acc = fmaf(A[k * 256 + i], A[k * 256 + j], acc);
  B0[i * 256 + j] = acc;
}

__global__ void k_bsq(const float* __restrict__ Bin, float* __restrict__ Bout) {
  __shared__ float diag[256];
  int i = blockIdx.x, j = threadIdx.x;
  diag[j] = Bin[j * 256 + j];
  __syncthreads();
  float tr = 0.f;
  for (int k = 0; k < 256; ++k) tr += diag[k];
  float inv = 1.0f / tr;
  float acc = 0.f;
  for (int k = 0; k < 256; ++k)
    acc = fmaf(Bin[i * 256 + k], Bin[k * 256 + j], acc);
  Bout[i * 256 + j] = acc * inv * inv;
}

__global__ void k_sfin(const float* __restrict__ Bf, const float* __restrict__ B0,
                       float* __restrict__ sinv) {
  __shared__ float v[256], w[256];
  __shared__ float red[256];
  __shared__ int redi[256];
  int t = threadIdx.x;
  // argmax of diagonal -> pick dominant column
  red[t] = Bf[t * 256 + t];
  redi[t] = t;
  __syncthreads();
  for (int s = 128; s > 0; s >>= 1) {
    if (t < s) {
      if (red[t + s] > red[t]) { red[t] = red[t + s]; redi[t] = redi[t + s]; }
    }
    __syncthreads();
  }
  int jmax = redi[0];
  __syncthreads();
  v[t] = Bf[t * 256 + jmax];
  __syncthreads();
  float acc = 0.f;
  for (int k = 0; k < 256; ++k) acc = fmaf(B0[t * 256 + k], v[k], acc);
  w[t] = acc;
  __syncthreads();
  red[t] = v[t] * w[t];
  __syncthreads();
  for (int s = 128; s > 0; s >>= 1) { if (t < s) red[t] += red[t + s]; __syncthreads(); }
  float num = red[0];
  __syncthreads();
  red[t] = v[t] * v[t];
  __syncthreads();
  for (int s = 128; s > 0; s >>= 1) { if (t < s) red[t] += red[t + s]; __syncthreads(); }
  if (t == 0) {
    float lam = num / red[0];       // = sigma^2
    float sg = sqrtf(lam);
    *sinv = 1.0f / (sg + 1e-5f);
  }
}

// ------------------------------------------------------------------
// Layer 1: y1 = w1 @ x + b1   (K = 3)
// ------------------------------------------------------------------
__global__ void k_conv1(const float* __restrict__ x, const float* __restrict__ w,
                        const float* __restrict__ bias, float* __restrict__ y) {
  int b = blockIdx.x >> 2;
  int n = ((blockIdx.x & 3) << 8) + threadIdx.x;
  const float* xb = x + (size_t)b * 3 * N_SZ;
  float x0 = xb[n], x1 = xb[N_SZ + n], x2 = xb[2 * N_SZ + n];
  float* yb = y + (size_t)b * C1 * N_SZ;
#pragma unroll 4
  for (int o = 0; o < C1; ++o) {
    float r = fmaf(w[o * 3 + 0], x0,
              fmaf(w[o * 3 + 1], x1,
              fmaf(w[o * 3 + 2], x2, bias[o])));
    yb[(size_t)o * N_SZ + n] = r;
  }
}

// ------------------------------------------------------------------
// Per-channel BN stats over (B, N): one block per channel -> affine coef.
// coef[c] = scale, coef[C+c] = shift  (h = relu(y*scale + shift))
// ------------------------------------------------------------------
__global__ void k_stats(const float* __restrict__ y, int C,
                        const float* __restrict__ g, const float* __restrict__ be,
                        float* __restrict__ coef) {
  int c = blockIdx.x;
  int t = threadIdx.x;
  float s1 = 0.f, s2 = 0.f;
  for (int b = 0; b < B_SZ; ++b) {
    const float4* p = (const float4*)(y + ((size_t)b * C + c) * N_SZ);
    float4 v = p[t];
    s1 += v.x + v.y + v.z + v.w;
    s2 += v.x * v.x + v.y * v.y + v.z * v.z + v.w * v.w;
  }
  __shared__ float r1[256], r2[256];
  r1[t] = s1; r2[t] = s2;
  __syncthreads();
  for (int s = 128; s > 0; s >>= 1) {
    if (t < s) { r1[t] += r1[t + s]; r2[t] += r2[t + s]; }
    __syncthreads();
  }
  if (t == 0) {
    const float M = (float)(B_SZ * N_SZ);
    float mu = r1[0] / M;
    float var = r2[0] / M - mu * mu;
    float sc = g[c] * rsqrtf(var + 1e-5f);
    coef[c] = sc;
    coef[C + c] = be[c] - mu * sc;
  }
}

// ------------------------------------------------------------------
// Tiled conv matmul: y[b][o][n] = sum_k w[o][k] * relu(hin[b][k][n]*sc+sh) + bias
// tile 64(o) x 64(n), Kt = 16, 256 threads, thread computes 4x4.
// ------------------------------------------------------------------
template <int K, int CO>
__global__ void k_conv(const float* __restrict__ hin, const float* __restrict__ coef,
                       const float* __restrict__ w, const float* __restrict__ bias,
                       float* __restrict__ y) {
  __shared__ float wt[64][17];
  __shared__ float ht[16][65];
  int b = blockIdx.x, ot = blockIdx.y, nt = blockIdx.z;
  int t = threadIdx.x;
  int tx = t & 15, ty = t >> 4;
  float acc[4][4] = {};
  const float* hb = hin + (size_t)b * K * N_SZ + nt * 64;
  for (int k0 = 0; k0 < K; k0 += 16) {
    {
      int r = t >> 2, cc = (t & 3) * 4;
      const float* wp = w + (size_t)(ot * 64 + r) * K + k0 + cc;
      wt[r][cc + 0] = wp[0]; wt[r][cc + 1] = wp[1];
      wt[r][cc + 2] = wp[2]; wt[r][cc + 3] = wp[3];
    }
    {
      int r = t >> 4, cc = (t & 15) * 4;
      float sc = coef[k0 + r], sh = coef[K + k0 + r];
      const float* hp = hb + (size_t)(k0 + r) * N_SZ + cc;
      ht[r][cc + 0] = fmaxf(fmaf(hp[0], sc, sh), 0.f);
      ht[r][cc + 1] = fmaxf(fmaf(hp[1], sc, sh), 0.f);
      ht[r][cc + 2] = fmaxf(fmaf(hp[2], sc, sh), 0.f);
      ht[r][cc + 3] = fmaxf(fmaf(hp[3], sc, sh), 0.f);
    }
    __syncthreads();
#pragma unroll
    for (int k = 0; k < 16; ++k) {
      float hv[4], wv[4];
#pragma unroll
      for (int j = 0; j < 4; ++j) hv[j] = ht[k][tx * 4 + j];
#pragma unroll
      for (int i = 0; i < 4; ++i) wv[i] = wt[ty * 4 + i][k];
#pragma unroll
      for (int i = 0; i < 4; ++i)
#pragma unroll
        for (int j = 0; j < 4; ++j) acc[i][j] = fmaf(wv[i], hv[j], acc[i][j]);
    }
    __syncthreads();
  }
  float* yb = y + ((size_t)b * CO + ot * 64) * N_SZ + nt * 64;
#pragma unroll
  for (int i = 0; i < 4; ++i) {
    float bv = bias[ot * 64 + ty * 4 + i];
    float4 v;
    v.x = acc[i][0] + bv; v.y = acc[i][1] + bv;
    v.z = acc[i][2] + bv; v.w = acc[i][3] + bv;
    *(float4*)(yb + (size_t)(ty * 4 + i) * N_SZ + tx * 4) = v;
  }
}

// ------------------------------------------------------------------
// uB[b][n][h] = sum_c relu(y3[b][c][n]*sc+sh) * Bm[h][c]
// tile: 64 n x 64 h, Kt=32. tx -> h(4), ty -> n(4).
// ------------------------------------------------------------------
__global__ void k_uB(const float* __restrict__ y3, const float* __restrict__ coef,
                     const float* __restrict__ Bm, float* __restrict__ uB) {
  __shared__ float xt[32][65];  // [c][n]
  __shared__ float bt[64][33];  // [h][c]
  int b = blockIdx.x, nt = blockIdx.y, htile = blockIdx.z;
  int t = threadIdx.x, tx = t & 15, ty = t >> 4;
  float acc[4][4] = {};  // [h][n]
  const float* yb = y3 + (size_t)b * C3 * N_SZ + nt * 64;
  for (int c0 = 0; c0 < C3; c0 += 32) {
#pragma unroll
    for (int rr = 0; rr < 2; ++rr) {
      int r = (t >> 4) + rr * 16;        // c within tile
      int cidx = c0 + r;
      float sc = coef[cidx], sh = coef[C3 + cidx];
      int cc = (t & 15) * 4;
      const float* p = yb + (size_t)cidx * N_SZ + cc;
      xt[r][cc + 0] = fmaxf(fmaf(p[0], sc, sh), 0.f);
      xt[r][cc + 1] = fmaxf(fmaf(p[1], sc, sh), 0.f);
      xt[r][cc + 2] = fmaxf(fmaf(p[2], sc, sh), 0.f);
      xt[r][cc + 3] = fmaxf(fmaf(p[3], sc, sh), 0.f);
    }
#pragma unroll
    for (int rr = 0; rr < 2; ++rr) {
      int r = (t >> 3) + rr * 32;        // h within tile
      int cc = (t & 7) * 4;
      const float* p = Bm + (size_t)(htile * 64 + r) * H_SZ + c0 + cc;
      bt[r][cc + 0] = p[0]; bt[r][cc + 1] = p[1];
      bt[r][cc + 2] = p[2]; bt[r][cc + 3] = p[3];
    }
    __syncthreads();
#pragma unroll
    for (int k = 0; k < 32; ++k) {
      float xv[4], bv[4];
#pragma unroll
      for (int j = 0; j < 4; ++j) xv[j] = xt[k][ty * 4 + j];
#pragma unroll
      for (int i = 0; i < 4; ++i) bv[i] = bt[tx * 4 + i][k];
#pragma unroll
      for (int i = 0; i < 4; ++i)
#pragma unroll
        for (int j = 0; j < 4; ++j) acc[i][j] = fmaf(bv[i], xv[j], acc[i][j]);
    }
    __syncthreads();
  }
  float* ob = uB + (size_t)b * N_SZ * H_SZ;
#pragma unroll
  for (int j = 0; j < 4; ++j) {
    float4 v;
    v.x = acc[0][j]; v.y = acc[1][j]; v.z = acc[2][j]; v.w = acc[3][j];
    *(float4*)(ob + (size_t)(nt * 64 + ty * 4 + j) * H_SZ + htile * 64 + tx * 4) = v;
  }
}

// ------------------------------------------------------------------
// Scan: 64 blocks (one per batch row), 1024 threads.
// A_norm in VGPRs (64 floats/thread), h broadcast through LDS.
// thread: lane = t&63, wv = t>>6; outputs i = lane + 64k (k=0..3),
// j-chunk = [wv*16, wv*16+16).
// ------------------------------------------------------------------
__global__ __launch_bounds__(1024, 4) void k_scan(
    const float* __restrict__ A, const float* __restrict__ sinvp,
    const float* __restrict__ uB, float* __restrict__ hs) {
  __shared__ float h_lds[256];
  __shared__ float part[16][257];
  const int b = blockIdx.x;
  const int t = threadIdx.x;
  const int lane = t & 63;
  const int wv = t >> 6;
  const float sinv = *sinvp;
  float a0[16], a1[16], a2[16], a3[16];
  {
    const float* r0 = A + (size_t)(lane) * 256 + wv * 16;
    const float* r1 = A + (size_t)(lane + 64) * 256 + wv * 16;
    const float* r2 = A + (size_t)(lane + 128) * 256 + wv * 16;
    const float* r3 = A + (size_t)(lane + 192) * 256 + wv * 16;
#pragma unroll
    for (int j = 0; j < 16; ++j) {
      a0[j] = r0[j] * sinv; a1[j] = r1[j] * sinv;
      a2[j] = r2[j] * sinv; a3[j] = r3[j] * sinv;
    }
  }
  if (t < 256) h_lds[t] = 0.f;
  __syncthreads();
  const float* ub = uB + (size_t)b * N_SZ * H_SZ;
  float* ho = hs + (size_t)b * N_SZ * H_SZ;
  float u_cur = (t < 256) ? ub[t] : 0.f;
  for (int s = 0; s < N_SZ; ++s) {
    float u_next = 0.f;
    if (t < 256 && s + 1 < N_SZ) u_next = ub[(size_t)(s + 1) * H_SZ + t];
    const float4* hp = ((const float4*)h_lds) + wv * 4;
    float acc0 = 0.f, acc1 = 0.f, acc2 = 0.f, acc3 = 0.f;
#pragma unroll
    for (int q = 0; q < 4; ++q) {
      const float4 h4 = hp[q];
      const int jb = q * 4;
      acc0 = fmaf(a0[jb + 0], h4.x, acc0);
      acc0 = fmaf(a0[jb + 1], h4.y, acc0);
      acc0 = fmaf(a0[jb + 2], h4.z, acc0);
      acc0 = fmaf(a0[jb + 3], h4.w, acc0);
      acc1 = fmaf(a1[jb + 0], h4.x, acc1);
      acc1 = fmaf(a1[jb + 1], h4.y, acc1);
      acc1 = fmaf(a1[jb + 2], h4.z, acc1);
      acc1 = fmaf(a1[jb + 3], h4.w, acc1);
      acc2 = fmaf(a2[jb + 0], h4.x, acc2);
      acc2 = fmaf(a2[jb + 1], h4.y, acc2);
      acc2 = fmaf(a2[jb + 2], h4.z, acc2);
      acc2 = fmaf(a2[jb + 3], h4.w, acc2);
      acc3 = fmaf(a3[jb + 0], h4.x, acc3);
      acc3 = fmaf(a3[jb + 1], h4.y, acc3);
      acc3 = fmaf(a3[jb + 2], h4.z, acc3);
      acc3 = fmaf(a3[jb + 3], h4.w, acc3);
    }
    part[wv][lane] = acc0;
    part[wv][lane + 64] = acc1;
    part[wv][lane + 128] = acc2;
    part[wv][lane + 192] = acc3;
    __syncthreads();
    if (t < 256) {
      float p = u_cur;
#pragma unroll
      for (int q = 0; q < 16; ++q) p += part[q][t];
      p = fmaxf(p, 0.f);
      h_lds[t] = p;
      ho[(size_t)s * H_SZ + t] = p;
    }
    u_cur = u_next;
    __syncthreads();
  }
}

// ------------------------------------------------------------------
// y[b][co][n] = sum_h hs[b][n][h] * Cm[co][h]
// tile 64 co x 64 n, Kt = 32. tx -> n(4), ty -> co(4).
// ------------------------------------------------------------------
__global__ void k_ymm(const float* __restrict__ hs, const float* __restrict__ Cm,
                      float* __restrict__ y) {
  __shared__ float st[64][33];  // [n][h-chunk]
  __shared__ float ct[64][33];  // [co][h-chunk]
  int b = blockIdx.x, ot = blockIdx.y, nt = blockIdx.z;
  int t = threadIdx.x, tx = t & 15, ty = t >> 4;
  float acc[4][4] = {};  // [co][n]
  const float* hb = hs + (size_t)b * N_SZ * H_SZ + (size_t)nt * 64 * H_SZ;
  for (int h0 = 0; h0 < H_SZ; h0 += 32) {
#pragma unroll
    for (int rr = 0; rr < 2; ++rr) {
      int r = (t >> 3) + rr * 32;
      int cc = (t & 7) * 4;
      const float* p = hb + (size_t)r * H_SZ + h0 + cc;
      st[r][cc + 0] = p[0]; st[r][cc + 1] = p[1];
      st[r][cc + 2] = p[2]; st[r][cc + 3] = p[3];
    }
#pragma unroll
    for (int rr = 0; rr < 2; ++rr) {
      int r = (t >> 3) + rr * 32;
      int cc = (t & 7) * 4;
      const float* p = Cm + (size_t)(ot * 64 + r) * H_SZ + h0 + cc;
      ct[r][cc + 0] = p[0]; ct[r][cc + 1] = p[1];
      ct[r][cc + 2] = p[2]; ct[r][cc + 3] = p[3];
    }
    __syncthreads();
#pragma unroll
    for (int k = 0; k < 32; ++k) {
      float sv[4], cv[4];
#pragma unroll
      for (int j = 0; j < 4; ++j) sv[j] = st[tx * 4 + j][k];
#pragma unroll
      for (int i = 0; i < 4; ++i) cv[i] = ct[ty * 4 + i][k];
#pragma unroll
      for (int i = 0; i < 4; ++i)
#pragma unroll
        for (int j = 0; j < 4; ++j) acc[i][j] = fmaf(cv[i], sv[j], acc[i][j]);
    }
    __syncthreads();
  }
  float* yb = y + ((size_t)b * C3 + ot * 64) * N_SZ + nt * 64;
#pragma unroll
  for (int i = 0; i < 4; ++i) {
    float4 v;
    v.x = acc[i][0]; v.y = acc[i][1]; v.z = acc[i][2]; v.w = acc[i][3];
    *(float4*)(yb + (size_t)(ty * 4 + i) * N_SZ + tx * 4) = v;
  }
}

// ------------------------------------------------------------------
extern "C" void kernel_launch(void* const* d_in, const int* in_sizes, int n_in,
                              void* d_out, int out_size, void* d_ws, size_t ws_size,
                              hipStream_t stream) {
  const float* x   = (const float*)d_in[0];
  const float* w1  = (const float*)d_in[1];
  const float* b1  = (const float*)d_in[2];
  const float* g1  = (const float*)d_in[3];
  const float* be1 = (const float*)d_in[4];
  const float* w2  = (const float*)d_in[5];
  const float* b2  = (const float*)d_in[6];
  const float* g2  = (const float*)d_in[7];
  const float* be2 = (const float*)d_in[8];
  const float* w3  = (const float*)d_in[9];
  const float* b3  = (const float*)d_in[10];
  const float* g3  = (const float*)d_in[11];
  const float* be3 = (const float*)d_in[12];
  const float* A   = (const float*)d_in[13];
  const float* Bm  = (const float*)d_in[14];
  const float* Cm  = (const float*)d_in[15];
  float* out = (float*)d_out;

  char* ws = (char*)d_ws;
  const size_t MB = 1024ull * 1024ull;
  float* y1 = (float*)(ws + 0);          // 16 MB
  float* y2 = (float*)(ws + 16 * MB);    // 32 MB
  float* y3 = (float*)(ws + 48 * MB);    // 64 MB
  float* hs = (float*)(ws + 0);          // 64 MB (y1,y2,y3 dead by scan time)
  char* sp = ws + 112 * MB;
  float* B0 = (float*)(sp);              // 256 KB
  float* P  = (float*)(sp + 256 * 1024);
  float* Q  = (float*)(sp + 512 * 1024);
  float* sinv  = (float*)(sp + 768 * 1024);
  float* coef1 = (float*)(sp + 768 * 1024 + 1024);
  float* coef2 = (float*)(sp + 768 * 1024 + 4096);
  float* coef3 = (float*)(sp + 768 * 1024 + 8192);

  // spectral norm of A
  k_btb<<<256, 256, 0, stream>>>(A, B0);
  {
    float* bufs[2] = {P, Q};
    const float* cur = B0;
    for (int it = 0; it < 12; ++it) {
      float* nxt = bufs[it & 1];
      k_bsq<<<256, 256, 0, stream>>>(cur, nxt);
      cur = nxt;
    }
    k_sfin<<<1, 256, 0, stream>>>(cur, B0, sinv);
  }

  // conv stack
  k_conv1<<<dim3(B_SZ * 4), 256, 0, stream>>>(x, w1, b1, y1);
  k_stats<<<C1, 256, 0, stream>>>(y1, C1, g1, be1, coef1);
  k_conv<C1, C2><<<dim3(B_SZ, C2 / 64, N_SZ / 64), 256, 0, stream>>>(y1, coef1, w2, b2, y2);
  k_stats<<<C2, 256, 0, stream>>>(y2, C2, g2, be2, coef2);
  k_conv<C2, C3><<<dim3(B_SZ, C3 / 64, N_SZ / 64), 256, 0, stream>>>(y2, coef2, w3, b3, y3);
  k_stats<<<C3, 256, 0, stream>>>(y3, C3, g3, be3, coef3);

  // uB = relu(bn(y3))^T @ Bm^T  -> stored in d_out (scratch until final matmul)
  k_uB<<<dim3(B_SZ, N_SZ / 64, H_SZ / 64), 256, 0, stream>>>(y3, coef3, Bm, out);

  // recurrent scan: h_t -> hs
  k_scan<<<dim3(B_SZ), 1024, 0, stream>>>(A, sinv, out, hs);

  // final projection
  k_ymm<<<dim3(B_SZ, C3 / 64, N_SZ / 64), 256, 0, stream>>>(hs, Cm, out);
}

// Round 2
// 1094.265 us; speedup vs baseline: 1.1559x; 1.1559x over previous
//
#include <hip/hip_runtime.h>

#define B_SZ 64
#define N_SZ 1024
#define C1   64
#define C2   128
#define C3   256
#define H_SZ 256

// ------------------------------------------------------------------
// Spectral norm of A (256x256) via repeated squaring of B = A^T A,
// then Rayleigh quotient against original B0.
// ------------------------------------------------------------------
__global__ void k_btb(const float* __restrict__ A, float* __restrict__ B0) {
  int i = blockIdx.x;    // 0..255
  int j = threadIdx.x;   // 0..255
  float acc = 0.f;
  for (int k = 0; k < 256; ++k)
    acc = fmaf(A[k * 256 + i], A[k * 256 + j], acc);
  B0[i * 256 + j] = acc;
}

__global__ void k_bsq(const float* __restrict__ Bin, float* __restrict__ Bout) {
  __shared__ float diag[256];
  int i = blockIdx.x, j = threadIdx.x;
  diag[j] = Bin[j * 256 + j];
  __syncthreads();
  float tr = 0.f;
  for (int k = 0; k < 256; ++k) tr += diag[k];
  float inv = 1.0f / tr;
  float acc = 0.f;
  for (int k = 0; k < 256; ++k)
    acc = fmaf(Bin[i * 256 + k], Bin[k * 256 + j], acc);
  Bout[i * 256 + j] = acc * inv * inv;
}

__global__ void k_sfin(const float* __restrict__ Bf, const float* __restrict__ B0,
                       float* __restrict__ sinv) {
  __shared__ float v[256], w[256];
  __shared__ float red[256];
  __shared__ int redi[256];
  int t = threadIdx.x;
  red[t] = Bf[t * 256 + t];
  redi[t] = t;
  __syncthreads();
  for (int s = 128; s > 0; s >>= 1) {
    if (t < s) {
      if (red[t + s] > red[t]) { red[t] = red[t + s]; redi[t] = redi[t + s]; }
    }
    __syncthreads();
  }
  int jmax = redi[0];
  __syncthreads();
  v[t] = Bf[t * 256 + jmax];
  __syncthreads();
  float acc = 0.f;
  for (int k = 0; k < 256; ++k) acc = fmaf(B0[t * 256 + k], v[k], acc);
  w[t] = acc;
  __syncthreads();
  red[t] = v[t] * w[t];
  __syncthreads();
  for (int s = 128; s > 0; s >>= 1) { if (t < s) red[t] += red[t + s]; __syncthreads(); }
  float num = red[0];
  __syncthreads();
  red[t] = v[t] * v[t];
  __syncthreads();
  for (int s = 128; s > 0; s >>= 1) { if (t < s) red[t] += red[t + s]; __syncthreads(); }
  if (t == 0) {
    float lam = num / red[0];       // = sigma^2
    float sg = sqrtf(lam);
    *sinv = 1.0f / (sg + 1e-5f);
  }
}

// ------------------------------------------------------------------
// Layer 1: y1 = w1 @ x + b1   (K = 3)
// ------------------------------------------------------------------
__global__ void k_conv1(const float* __restrict__ x, const float* __restrict__ w,
                        const float* __restrict__ bias, float* __restrict__ y) {
  int b = blockIdx.x >> 2;
  int n = ((blockIdx.x & 3) << 8) + threadIdx.x;
  const float* xb = x + (size_t)b * 3 * N_SZ;
  float x0 = xb[n], x1 = xb[N_SZ + n], x2 = xb[2 * N_SZ + n];
  float* yb = y + (size_t)b * C1 * N_SZ;
#pragma unroll 4
  for (int o = 0; o < C1; ++o) {
    float r = fmaf(w[o * 3 + 0], x0,
              fmaf(w[o * 3 + 1], x1,
              fmaf(w[o * 3 + 2], x2, bias[o])));
    yb[(size_t)o * N_SZ + n] = r;
  }
}

// ------------------------------------------------------------------
// Per-channel BN stats over (B, N) -> affine coef.
// ------------------------------------------------------------------
__global__ void k_stats(const float* __restrict__ y, int C,
                        const float* __restrict__ g, const float* __restrict__ be,
                        float* __restrict__ coef) {
  int c = blockIdx.x;
  int t = threadIdx.x;
  float s1 = 0.f, s2 = 0.f;
  for (int b = 0; b < B_SZ; ++b) {
    const float4* p = (const float4*)(y + ((size_t)b * C + c) * N_SZ);
    float4 v = p[t];
    s1 += v.x + v.y + v.z + v.w;
    s2 += v.x * v.x + v.y * v.y + v.z * v.z + v.w * v.w;
  }
  __shared__ float r1[256], r2[256];
  r1[t] = s1; r2[t] = s2;
  __syncthreads();
  for (int s = 128; s > 0; s >>= 1) {
    if (t < s) { r1[t] += r1[t + s]; r2[t] += r2[t + s]; }
    __syncthreads();
  }
  if (t == 0) {
    const float M = (float)(B_SZ * N_SZ);
    float mu = r1[0] / M;
    float var = r2[0] / M - mu * mu;
    float sc = g[c] * rsqrtf(var + 1e-5f);
    coef[c] = sc;
    coef[C + c] = be[c] - mu * sc;
  }
}

// ------------------------------------------------------------------
// Tiled conv matmul: y[b][o][n] = sum_k w[o][k]*relu(bn(hin[b][k][n])) + bias
// LDS layouts transposed to [k][*] so inner loop is 2x ds_read_b128.
// ------------------------------------------------------------------
template <int K, int CO>
__global__ void k_conv(const float* __restrict__ hin, const float* __restrict__ coef,
                       const float* __restrict__ w, const float* __restrict__ bias,
                       float* __restrict__ y) {
  __shared__ float wt2[16][68];  // [k][o]
  __shared__ float ht[16][68];   // [k][n]
  int b = blockIdx.x, ot = blockIdx.y, nt = blockIdx.z;
  int t = threadIdx.x;
  int tx = t & 15, ty = t >> 4;
  float acc[4][4] = {};
  const float* hb = hin + (size_t)b * K * N_SZ + nt * 64;
  for (int k0 = 0; k0 < K; k0 += 16) {
    {
      int r = t >> 2, cc = (t & 3) * 4;    // r: o 0..63, cc: k
      float4 v = *(const float4*)(w + (size_t)(ot * 64 + r) * K + k0 + cc);
      wt2[cc + 0][r] = v.x; wt2[cc + 1][r] = v.y;
      wt2[cc + 2][r] = v.z; wt2[cc + 3][r] = v.w;
    }
    {
      int r = t >> 4, cc = (t & 15) * 4;   // r: k 0..15, cc: n
      float sc = coef[k0 + r], sh = coef[K + k0 + r];
      const float* hp = hb + (size_t)(k0 + r) * N_SZ + cc;
      float4 v;
      v.x = fmaxf(fmaf(hp[0], sc, sh), 0.f);
      v.y = fmaxf(fmaf(hp[1], sc, sh), 0.f);
      v.z = fmaxf(fmaf(hp[2], sc, sh), 0.f);
      v.w = fmaxf(fmaf(hp[3], sc, sh), 0.f);
      *(float4*)&ht[r][cc] = v;
    }
    __syncthreads();
#pragma unroll
    for (int k = 0; k < 16; ++k) {
      float4 hv = *(const float4*)&ht[k][tx * 4];
      float4 wv = *(const float4*)&wt2[k][ty * 4];
      float hvv[4] = {hv.x, hv.y, hv.z, hv.w};
      float wvv[4] = {wv.x, wv.y, wv.z, wv.w};
#pragma unroll
      for (int i = 0; i < 4; ++i)
#pragma unroll
        for (int j = 0; j < 4; ++j) acc[i][j] = fmaf(wvv[i], hvv[j], acc[i][j]);
    }
    __syncthreads();
  }
  float* yb = y + ((size_t)b * CO + ot * 64) * N_SZ + nt * 64;
#pragma unroll
  for (int i = 0; i < 4; ++i) {
    float bv = bias[ot * 64 + ty * 4 + i];
    float4 v;
    v.x = acc[i][0] + bv; v.y = acc[i][1] + bv;
    v.z = acc[i][2] + bv; v.w = acc[i][3] + bv;
    *(float4*)(yb + (size_t)(ty * 4 + i) * N_SZ + tx * 4) = v;
  }
}

// ------------------------------------------------------------------
// uB[b][n][h] = sum_c relu(bn(y3[b][c][n])) * Bm[h][c]
// xt: [c][n] (k-major already), bt2: [c][h] transposed.
// ------------------------------------------------------------------
__global__ void k_uB(const float* __restrict__ y3, const float* __restrict__ coef,
                     const float* __restrict__ Bm, float* __restrict__ uB) {
  __shared__ float xt[32][68];   // [c][n]
  __shared__ float bt2[32][68];  // [c][h]
  int b = blockIdx.x, nt = blockIdx.y, htile = blockIdx.z;
  int t = threadIdx.x, tx = t & 15, ty = t >> 4;
  float acc[4][4] = {};  // [h][n]
  const float* yb = y3 + (size_t)b * C3 * N_SZ + nt * 64;
  for (int c0 = 0; c0 < C3; c0 += 32) {
#pragma unroll
    for (int rr = 0; rr < 2; ++rr) {
      int r = (t >> 4) + rr * 16;        // c within tile
      int cidx = c0 + r;
      float sc = coef[cidx], sh = coef[C3 + cidx];
      int cc = (t & 15) * 4;
      const float* p = yb + (size_t)cidx * N_SZ + cc;
      float4 v;
      v.x = fmaxf(fmaf(p[0], sc, sh), 0.f);
      v.y = fmaxf(fmaf(p[1], sc, sh), 0.f);
      v.z = fmaxf(fmaf(p[2], sc, sh), 0.f);
      v.w = fmaxf(fmaf(p[3], sc, sh), 0.f);
      *(float4*)&xt[r][cc] = v;
    }
#pragma unroll
    for (int rr = 0; rr < 2; ++rr) {
      int r = (t >> 3) + rr * 32;        // h within tile 0..63
      int cc = (t & 7) * 4;              // c chunk
      float4 v = *(const float4*)(Bm + (size_t)(htile * 64 + r) * H_SZ + c0 + cc);
      bt2[cc + 0][r] = v.x; bt2[cc + 1][r] = v.y;
      bt2[cc + 2][r] = v.z; bt2[cc + 3][r] = v.w;
    }
    __syncthreads();
#pragma unroll
    for (int k = 0; k < 32; ++k) {
      float4 xv = *(const float4*)&xt[k][ty * 4];
      float4 bv = *(const float4*)&bt2[k][tx * 4];
      float xvv[4] = {xv.x, xv.y, xv.z, xv.w};
      float bvv[4] = {bv.x, bv.y, bv.z, bv.w};
#pragma unroll
      for (int i = 0; i < 4; ++i)
#pragma unroll
        for (int j = 0; j < 4; ++j) acc[i][j] = fmaf(bvv[i], xvv[j], acc[i][j]);
    }
    __syncthreads();
  }
  float* ob = uB + (size_t)b * N_SZ * H_SZ;
#pragma unroll
  for (int j = 0; j < 4; ++j) {
    float4 v;
    v.x = acc[0][j]; v.y = acc[1][j]; v.z = acc[2][j]; v.w = acc[3][j];
    *(float4*)(ob + (size_t)(nt * 64 + ty * 4 + j) * H_SZ + htile * 64 + tx * 4) = v;
  }
}

// ------------------------------------------------------------------
// Scan: 64 blocks (one per batch row), 512 threads (8 waves).
// Thread (w,l): outputs i = l + 64k (k=0..3), j-chunk [32w, 32w+32).
// 128 A coeffs in VGPRs; h broadcast via LDS; depth-8 reduce.
// ------------------------------------------------------------------
__global__ __launch_bounds__(512, 2) void k_scan(
    const float* __restrict__ A, const float* __restrict__ sinvp,
    const float* __restrict__ uB, float* __restrict__ hs) {
  __shared__ float h_lds[256];
  __shared__ float part[8][256];
  const int b = blockIdx.x;
  const int t = threadIdx.x;
  const int lane = t & 63;
  const int wv = t >> 6;       // 0..7
  const float sinv = *sinvp;
  float areg[4][32];
#pragma unroll
  for (int k = 0; k < 4; ++k) {
    const float* r = A + (size_t)(lane + 64 * k) * 256 + wv * 32;
#pragma unroll
    for (int j = 0; j < 32; ++j) areg[k][j] = r[j] * sinv;
  }
  if (t < 256) h_lds[t] = 0.f;
  __syncthreads();
  const float* ub = uB + (size_t)b * N_SZ * H_SZ;
  float* ho = hs + (size_t)b * N_SZ * H_SZ;
  float u_cur = (t < 256) ? ub[t] : 0.f;
  for (int s = 0; s < N_SZ; ++s) {
    float u_next = 0.f;
    if (t < 256 && s + 1 < N_SZ) u_next = ub[(size_t)(s + 1) * H_SZ + t];
    const float4* hp = ((const float4*)h_lds) + wv * 8;
    float acc[4] = {0.f, 0.f, 0.f, 0.f};
#pragma unroll
    for (int q = 0; q < 8; ++q) {
      const float4 h4 = hp[q];
#pragma unroll
      for (int k = 0; k < 4; ++k) {
        acc[k] = fmaf(areg[k][q * 4 + 0], h4.x, acc[k]);
        acc[k] = fmaf(areg[k][q * 4 + 1], h4.y, acc[k]);
        acc[k] = fmaf(areg[k][q * 4 + 2], h4.z, acc[k]);
        acc[k] = fmaf(areg[k][q * 4 + 3], h4.w, acc[k]);
      }
    }
    part[wv][lane] = acc[0];
    part[wv][lane + 64] = acc[1];
    part[wv][lane + 128] = acc[2];
    part[wv][lane + 192] = acc[3];
    __syncthreads();
    if (t < 256) {
      float p = u_cur;
#pragma unroll
      for (int c = 0; c < 8; ++c) p += part[c][t];
      p = fmaxf(p, 0.f);
      h_lds[t] = p;
      ho[(size_t)s * H_SZ + t] = p;
    }
    u_cur = u_next;
    __syncthreads();
  }
}

// ------------------------------------------------------------------
// y[b][co][n] = sum_h hs[b][n][h] * Cm[co][h]
// st2: [h][n] transposed, ct2: [h][co] transposed.
// ------------------------------------------------------------------
__global__ void k_ymm(const float* __restrict__ hs, const float* __restrict__ Cm,
                      float* __restrict__ y) {
  __shared__ float st2[32][68];  // [h-k][n]
  __shared__ float ct2[32][68];  // [h-k][co]
  int b = blockIdx.x, ot = blockIdx.y, nt = blockIdx.z;
  int t = threadIdx.x, tx = t & 15, ty = t >> 4;
  float acc[4][4] = {};  // [co][n]
  const float* hb = hs + (size_t)b * N_SZ * H_SZ + (size_t)nt * 64 * H_SZ;
  for (int h0 = 0; h0 < H_SZ; h0 += 32) {
#pragma unroll
    for (int rr = 0; rr < 2; ++rr) {
      int r = (t >> 3) + rr * 32;   // n row 0..63
      int cc = (t & 7) * 4;         // h chunk
      float4 v = *(const float4*)(hb + (size_t)r * H_SZ + h0 + cc);
      st2[cc + 0][r] = v.x; st2[cc + 1][r] = v.y;
      st2[cc + 2][r] = v.z; st2[cc + 3][r] = v.w;
    }
#pragma unroll
    for (int rr = 0; rr < 2; ++rr) {
      int r = (t >> 3) + rr * 32;   // co row 0..63
      int cc = (t & 7) * 4;
      float4 v = *(const float4*)(Cm + (size_t)(ot * 64 + r) * H_SZ + h0 + cc);
      ct2[cc + 0][r] = v.x; ct2[cc + 1][r] = v.y;
      ct2[cc + 2][r] = v.z; ct2[cc + 3][r] = v.w;
    }
    __syncthreads();
#pragma unroll
    for (int k = 0; k < 32; ++k) {
      float4 sv = *(const float4*)&st2[k][tx * 4];
      float4 cv = *(const float4*)&ct2[k][ty * 4];
      float svv[4] = {sv.x, sv.y, sv.z, sv.w};
      float cvv[4] = {cv.x, cv.y, cv.z, cv.w};
#pragma unroll
      for (int i = 0; i < 4; ++i)
#pragma unroll
        for (int j = 0; j < 4; ++j) acc[i][j] = fmaf(cvv[i], svv[j], acc[i][j]);
    }
    __syncthreads();
  }
  float* yb = y + ((size_t)b * C3 + ot * 64) * N_SZ + nt * 64;
#pragma unroll
  for (int i = 0; i < 4; ++i) {
    float4 v;
    v.x = acc[i][0]; v.y = acc[i][1]; v.z = acc[i][2]; v.w = acc[i][3];
    *(float4*)(yb + (size_t)(ty * 4 + i) * N_SZ + tx * 4) = v;
  }
}

// ------------------------------------------------------------------
extern "C" void kernel_launch(void* const* d_in, const int* in_sizes, int n_in,
                              void* d_out, int out_size, void* d_ws, size_t ws_size,
                              hipStream_t stream) {
  const float* x   = (const float*)d_in[0];
  const float* w1  = (const float*)d_in[1];
  const float* b1  = (const float*)d_in[2];
  const float* g1  = (const float*)d_in[3];
  const float* be1 = (const float*)d_in[4];
  const float* w2  = (const float*)d_in[5];
  const float* b2  = (const float*)d_in[6];
  const float* g2  = (const float*)d_in[7];
  const float* be2 = (const float*)d_in[8];
  const float* w3  = (const float*)d_in[9];
  const float* b3  = (const float*)d_in[10];
  const float* g3  = (const float*)d_in[11];
  const float* be3 = (const float*)d_in[12];
  const float* A   = (const float*)d_in[13];
  const float* Bm  = (const float*)d_in[14];
  const float* Cm  = (const float*)d_in[15];
  float* out = (float*)d_out;

  char* ws = (char*)d_ws;
  const size_t MB = 1024ull * 1024ull;
  float* y1 = (float*)(ws + 0);          // 16 MB
  float* y2 = (float*)(ws + 16 * MB);    // 32 MB
  float* y3 = (float*)(ws + 48 * MB);    // 64 MB
  float* hs = (float*)(ws + 0);          // 64 MB (y1,y2 dead by scan time)
  char* sp = ws + 112 * MB;
  float* B0 = (float*)(sp);              // 256 KB
  float* P  = (float*)(sp + 256 * 1024);
  float* Q  = (float*)(sp + 512 * 1024);
  float* sinv  = (float*)(sp + 768 * 1024);
  float* coef1 = (float*)(sp + 768 * 1024 + 1024);
  float* coef2 = (float*)(sp + 768 * 1024 + 4096);
  float* coef3 = (float*)(sp + 768 * 1024 + 8192);

  // spectral norm of A
  k_btb<<<256, 256, 0, stream>>>(A, B0);
  {
    float* bufs[2] = {P, Q};
    const float* cur = B0;
    for (int it = 0; it < 12; ++it) {
      float* nxt = bufs[it & 1];
      k_bsq<<<256, 256, 0, stream>>>(cur, nxt);
      cur = nxt;
    }
    k_sfin<<<1, 256, 0, stream>>>(cur, B0, sinv);
  }

  // conv stack
  k_conv1<<<dim3(B_SZ * 4), 256, 0, stream>>>(x, w1, b1, y1);
  k_stats<<<C1, 256, 0, stream>>>(y1, C1, g1, be1, coef1);
  k_conv<C1, C2><<<dim3(B_SZ, C2 / 64, N_SZ / 64), 256, 0, stream>>>(y1, coef1, w2, b2, y2);
  k_stats<<<C2, 256, 0, stream>>>(y2, C2, g2, be2, coef2);
  k_conv<C2, C3><<<dim3(B_SZ, C3 / 64, N_SZ / 64), 256, 0, stream>>>(y2, coef2, w3, b3, y3);
  k_stats<<<C3, 256, 0, stream>>>(y3, C3, g3, be3, coef3);

  // uB -> d_out (scratch until final matmul)
  k_uB<<<dim3(B_SZ, N_SZ / 64, H_SZ / 64), 256, 0, stream>>>(y3, coef3, Bm, out);

  // recurrent scan
  k_scan<<<dim3(B_SZ), 512, 0, stream>>>(A, sinv, out, hs);

  // final projection
  k_ymm<<<dim3(B_SZ, C3 / 64, N_SZ / 64), 256, 0, stream>>>(hs, Cm, out);
}